// Round 1
// baseline (622.708 us; speedup 1.0000x reference)
//
#include <hip/hip_runtime.h>

typedef __attribute__((ext_vector_type(8))) short short8;
typedef __attribute__((ext_vector_type(4))) short short4v;
typedef __attribute__((ext_vector_type(4))) float float4v;

static __device__ __forceinline__ unsigned short f2bf(float f) {
  unsigned int u = __float_as_uint(f);
  u = (u + 0x7fffu + ((u >> 16) & 1u)) >> 16;   // RNE
  return (unsigned short)u;
}

static __device__ __forceinline__ short8 pack8(float4v a, float4v b) {
  short8 r;
  r[0] = (short)f2bf(a.x); r[1] = (short)f2bf(a.y);
  r[2] = (short)f2bf(a.z); r[3] = (short)f2bf(a.w);
  r[4] = (short)f2bf(b.x); r[5] = (short)f2bf(b.y);
  r[6] = (short)f2bf(b.z); r[7] = (short)f2bf(b.w);
  return r;
}
static __device__ __forceinline__ short4v pack4(float4v a) {
  short4v r;
  r[0] = (short)f2bf(a.x); r[1] = (short)f2bf(a.y);
  r[2] = (short)f2bf(a.z); r[3] = (short)f2bf(a.w);
  return r;
}

// sigmoid(x) ~ 0.5 + x*(0.25 + s1*x^2 + s2*x^4) on [-2.4,2.4]; gate preacts are |x|<~0.8
static __device__ __forceinline__ float sig_poly(float x) {
  x = fminf(2.4f, fmaxf(-2.4f, x));
  float x2 = x * x;
  float t = fmaf(0.0010218f, x2, -0.0191312f);
  t = fmaf(t, x2, 0.25f);
  return fmaf(x, t, 0.5f);
}
// tanh(x) ~ x*(1 + c1*x^2 + c2*x^4) on [-1.2,1.2]
static __device__ __forceinline__ float tanh_poly(float x) {
  x = fminf(1.2f, fmaxf(-1.2f, x));
  float x2 = x * x;
  float t = fmaf(0.0654f, x2, -0.3061f);
  t = fmaf(t, x2, 1.0f);
  return x * t;
}

#define MFMA16x16(a, b, c) __builtin_amdgcn_mfma_f32_16x16x32_bf16((a), (b), (c), 0, 0, 0)

// Block = 256 threads (4 waves), 64 rows/block, 16 rows/wave.
// LDS total 63488 B -> 2 blocks/CU.
__global__ __launch_bounds__(256, 2) void tie_kernel(
    const float* __restrict__ emb, const float* __restrict__ cent,
    const float* __restrict__ Wih, const float* __restrict__ Whh,
    const float* __restrict__ bih, const float* __restrict__ bhh,
    const float* __restrict__ Wt, const float* __restrict__ bt,
    const float* __restrict__ Wa, const float* __restrict__ ba,
    const float* __restrict__ Wf, const float* __restrict__ bfv,
    float* __restrict__ out)
{
  __shared__ short fused_in[64][264];   // [appear(0:128) | traj(128:256)] bf16, +8 pad (bank skew)
  __shared__ short h_stage[64][72];     // h bf16 A-stage, +8 pad
  __shared__ short wscratch[10240];     // Wa dbuf 2*[128][40] / Wf chunk [128][72]

  const int tid = (int)threadIdx.x;
  const int lane = tid & 63;
  const int wv = tid >> 6;
  const int c = lane & 15;              // MFMA: A-row / B-col / C-col index
  const int q = lane >> 4;              // MFMA quad
  const int r0 = wv * 16;               // wave-local row base
  const long rowblk = (long)blockIdx.x * 64;

  // ---- zero own h rows (h0 = 0); per-wave private -> no barrier needed ----
  {
    short4v z = {0, 0, 0, 0};
    short4v* hp = (short4v*)&h_stage[r0][0];
    for (int i = lane; i < 288; i += 64) hp[i] = z;
  }

  // ---- per-lane GRU constants (biases folded into MFMA acc init) ----
  float accb_r[4], accb_z[4], accb_n[4], bxn[4];
  float wr0[4], wr1[4], wz0[4], wz1[4], wn0[4], wn1[4];
#pragma unroll
  for (int t = 0; t < 4; ++t) {
    int gr = t * 16 + c, gz = 64 + t * 16 + c, gn = 128 + t * 16 + c;
    accb_r[t] = bih[gr] + bhh[gr];
    accb_z[t] = bih[gz] + bhh[gz];
    accb_n[t] = bhh[gn];          // n-gate: r multiplies (hn + b_hh) only
    bxn[t] = bih[gn];
    wr0[t] = Wih[2 * gr]; wr1[t] = Wih[2 * gr + 1];
    wz0[t] = Wih[2 * gz]; wz1[t] = Wih[2 * gz + 1];
    wn0[t] = Wih[2 * gn]; wn1[t] = Wih[2 * gn + 1];
  }

  // ---- preload W_hh B-fragments (B[k][g] = W_hh[g][k], contiguous rows) ----
  short8 whhf[12][2];
#pragma unroll
  for (int nt = 0; nt < 12; ++nt) {
    const float* wp = Whh + (long)(nt * 16 + c) * 64 + q * 8;
    whhf[nt][0] = pack8(*(const float4v*)(wp), *(const float4v*)(wp + 4));
    whhf[nt][1] = pack8(*(const float4v*)(wp + 32), *(const float4v*)(wp + 36));
  }

  // ---- GRU: 16 steps, barrier-free (wave-private LDS region) ----
  const float* cbase = cent + (rowblk + r0 + q * 4) * 32;
  float hprev[4][4];
#pragma unroll
  for (int t = 0; t < 4; ++t)
#pragma unroll
    for (int g = 0; g < 4; ++g) hprev[t][g] = 0.0f;

  float x0[4], x1[4];
#pragma unroll
  for (int g = 0; g < 4; ++g) {
    float2 xv = *(const float2*)(cbase + g * 32);
    x0[g] = xv.x; x1[g] = xv.y;
  }

  for (int s = 0; s < 16; ++s) {
    short8 a0 = *(const short8*)&h_stage[r0 + c][q * 8];
    short8 a1 = *(const short8*)&h_stage[r0 + c][32 + q * 8];
    float4v acc[12];
#pragma unroll
    for (int t = 0; t < 4; ++t) {
      acc[t]     = (float4v){accb_r[t], accb_r[t], accb_r[t], accb_r[t]};
      acc[t + 4] = (float4v){accb_z[t], accb_z[t], accb_z[t], accb_z[t]};
      acc[t + 8] = (float4v){accb_n[t], accb_n[t], accb_n[t], accb_n[t]};
    }
#pragma unroll
    for (int nt = 0; nt < 12; ++nt) {
      acc[nt] = MFMA16x16(a0, whhf[nt][0], acc[nt]);
      acc[nt] = MFMA16x16(a1, whhf[nt][1], acc[nt]);
    }
    float nx0[4], nx1[4];
    if (s < 15) {
#pragma unroll
      for (int g = 0; g < 4; ++g) {
        float2 xv = *(const float2*)(cbase + g * 32 + (s + 1) * 2);
        nx0[g] = xv.x; nx1[g] = xv.y;
      }
    }
#pragma unroll
    for (int t = 0; t < 4; ++t) {
#pragma unroll
      for (int g = 0; g < 4; ++g) {
        float hr = acc[t][g], hz = acc[t + 4][g], hn = acc[t + 8][g];
        float r = sig_poly(fmaf(wr0[t], x0[g], fmaf(wr1[t], x1[g], hr)));
        float z = sig_poly(fmaf(wz0[t], x0[g], fmaf(wz1[t], x1[g], hz)));
        float xn = fmaf(wn0[t], x0[g], fmaf(wn1[t], x1[g], bxn[t]));
        float n = tanh_poly(fmaf(r, hn, xn));
        float h = fmaf(z, hprev[t][g] - n, n);
        hprev[t][g] = h;
        h_stage[r0 + q * 4 + g][t * 16 + c] = (short)f2bf(h);
      }
    }
    if (s < 15) {
#pragma unroll
      for (int g = 0; g < 4; ++g) { x0[g] = nx0[g]; x1[g] = nx1[g]; }
    }
  }

  // ---- traj proj: h_last @ Wt^T + bt -> fused_in[:,128:256] (Wt frags from L2) ----
  {
    short8 a0 = *(const short8*)&h_stage[r0 + c][q * 8];
    short8 a1 = *(const short8*)&h_stage[r0 + c][32 + q * 8];
#pragma unroll
    for (int nt = 0; nt < 8; ++nt) {
      int col = nt * 16 + c;
      const float* wp = Wt + (long)col * 64 + q * 8;
      short8 b0 = pack8(*(const float4v*)(wp), *(const float4v*)(wp + 4));
      short8 b1 = pack8(*(const float4v*)(wp + 32), *(const float4v*)(wp + 36));
      float bv = bt[col];
      float4v acc = (float4v){bv, bv, bv, bv};
      acc = MFMA16x16(a0, b0, acc);
      acc = MFMA16x16(a1, b1, acc);
#pragma unroll
      for (int g = 0; g < 4; ++g)
        fused_in[r0 + q * 4 + g][128 + col] = (short)f2bf(acc[g]);
    }
  }

  // ---- appearance proj: stream emb (268 MB), Wa chunks dbuf in LDS ----
  {
    short (*wa0)[40] = (short(*)[40])(&wscratch[0]);
    short (*wa1)[40] = (short(*)[40])(&wscratch[5120]);
    float4v accA[8];
#pragma unroll
    for (int nt = 0; nt < 8; ++nt) {
      float bv = ba[nt * 16 + c];
      accA[nt] = (float4v){bv, bv, bv, bv};
    }
    const float* erow = emb + (rowblk + r0 + c) * 512;  // A-frag row m = c
    float4v e0 = *(const float4v*)(erow + q * 8);
    float4v e1 = *(const float4v*)(erow + q * 8 + 4);
    for (int kc = 0; kc < 16; ++kc) {
      short (*buf)[40] = (kc & 1) ? wa1 : wa0;
#pragma unroll
      for (int j = 0; j < 4; ++j) {           // stage Wa[:, kc*32:+32] -> bf16 LDS
        int f4 = tid + j * 256;
        int n = f4 >> 3, c4 = f4 & 7;
        float4v v = *(const float4v*)(Wa + (long)n * 512 + kc * 32 + c4 * 4);
        *(short4v*)&buf[n][c4 * 4] = pack4(v);
      }
      float4v p0 = e0, p1 = e1;
      if (kc < 15) {                           // prefetch next emb fragment
        p0 = *(const float4v*)(erow + (kc + 1) * 32 + q * 8);
        p1 = *(const float4v*)(erow + (kc + 1) * 32 + q * 8 + 4);
      }
      __syncthreads();
      short8 ea = pack8(e0, e1);
#pragma unroll
      for (int nt = 0; nt < 8; ++nt) {
        short8 wb = *(const short8*)&buf[nt * 16 + c][q * 8];
        accA[nt] = MFMA16x16(ea, wb, accA[nt]);
      }
      e0 = p0; e1 = p1;
    }
#pragma unroll
    for (int nt = 0; nt < 8; ++nt)
#pragma unroll
      for (int g = 0; g < 4; ++g)
        fused_in[r0 + q * 4 + g][nt * 16 + c] = (short)f2bf(accA[nt][g]);
  }
  __syncthreads();

  // ---- fuse: [appear|traj] @ Wf^T + bf, exact GELU ----
  {
    short (*wf_s)[72] = (short(*)[72])wscratch;
    float4v accF[8];
#pragma unroll
    for (int nt = 0; nt < 8; ++nt) {
      float bv = bfv[nt * 16 + c];
      accF[nt] = (float4v){bv, bv, bv, bv};
    }
    for (int kc = 0; kc < 4; ++kc) {
      if (kc) __syncthreads();
#pragma unroll
      for (int j = 0; j < 8; ++j) {           // stage Wf[:, kc*64:+64]
        int f4 = tid + j * 256;
        int n = f4 >> 4, c4 = f4 & 15;
        float4v v = *(const float4v*)(Wf + (long)n * 256 + kc * 64 + c4 * 4);
        *(short4v*)&wf_s[n][c4 * 4] = pack4(v);
      }
      __syncthreads();
#pragma unroll
      for (int ki = 0; ki < 2; ++ki) {
        short8 fa = *(const short8*)&fused_in[r0 + c][kc * 64 + ki * 32 + q * 8];
#pragma unroll
        for (int nt = 0; nt < 8; ++nt) {
          short8 wb = *(const short8*)&wf_s[nt * 16 + c][ki * 32 + q * 8];
          accF[nt] = MFMA16x16(fa, wb, accF[nt]);
        }
      }
    }
    float* orow = out + (rowblk + r0 + q * 4) * 128;
#pragma unroll
    for (int nt = 0; nt < 8; ++nt) {
#pragma unroll
      for (int g = 0; g < 4; ++g) {
        float xv = accF[nt][g];
        float gl = 0.5f * xv * (1.0f + erff(xv * 0.70710678f));
        orow[(long)g * 128 + nt * 16 + c] = gl;
      }
    }
  }
}

extern "C" void kernel_launch(void* const* d_in, const int* in_sizes, int n_in,
                              void* d_out, int out_size, void* d_ws, size_t ws_size,
                              hipStream_t stream) {
  const float* emb = (const float*)d_in[0];
  const float* cent = (const float*)d_in[1];
  const float* Wih = (const float*)d_in[2];
  const float* Whh = (const float*)d_in[3];
  const float* bih = (const float*)d_in[4];
  const float* bhh = (const float*)d_in[5];
  const float* Wt  = (const float*)d_in[6];
  const float* bt  = (const float*)d_in[7];
  const float* Wa  = (const float*)d_in[8];
  const float* ba  = (const float*)d_in[9];
  const float* Wf  = (const float*)d_in[10];
  const float* bfv = (const float*)d_in[11];
  float* out = (float*)d_out;

  const int B = in_sizes[0] / 512;       // 131072
  dim3 grid(B / 64), block(256);
  hipLaunchKernelGGL(tie_kernel, grid, block, 0, stream,
                     emb, cent, Wih, Whh, bih, bhh, Wt, bt, Wa, ba, Wf, bfv, out);
}